// Round 6
// baseline (107.161 us; speedup 1.0000x reference)
//
#include <hip/hip_runtime.h>
#include <hip/hip_bf16.h>

// Problem: B=32, S=512, P=512, D=768
//   M = B*S = 16384 tokens, N = P = 512 prototypes, K = D = 768
// out[0 .. M*N)            = distances  ||x_m - p_n||^2  (fp32)
// out[M*N .. M*N + N*K)    = prototypes (fp32 passthrough)
//
// R11 = R10 (fragment-major B, verified: dist_main 44->~31us) with 32-row
// stripes -> 2 blocks/CU.
//   R10 post-mortem: with coalesced B, dist_main is a 3-phase serial convoy
//   per CU (stage ~8us | K-loop ~16us | epilogue ~5us) because 97.5KB LDS
//   forces 1 block/CU. Halving the A-stripe (32 tok x full-K = 48.7KB LDS)
//   lets 2 blocks co-reside: one block's staging/epilogue overlaps the
//   other's K-loop. Per-wave K-loop schedule, single barrier, fragment-major
//   B stream, epilogue layout all unchanged from R10 (wave now owns
//   32 tok x 64 protos: acc[2][4], af[2]).
//   X still read exactly once (disjoint stripes). B re-read 2x -> 402MB,
//   but B = 768KB = L2-resident per XCD; overlappable.

#define M_TOK 16384
#define N_PROT 512
#define K_DIM 768
#define BK 32
#define NCH (K_DIM / BK)     // 24
#define ASTR (K_DIM + 8)     // 776: padded LDS row stride in bf16 units

typedef __attribute__((ext_vector_type(4))) float f32x4;
typedef __attribute__((ext_vector_type(8))) short bf16x8;

__device__ inline unsigned short f2bf(float f) {
    // round-to-nearest-even on the bit pattern (finite inputs)
    unsigned int u = __float_as_uint(f);
    u += 0x7fffu + ((u >> 16) & 1u);
    return (unsigned short)(u >> 16);
}

// One wave per prototype row: bf16 convert (fragment-major store) + ||p||^2
// + fp32 passthrough copy.  (unchanged from verified R10)
__global__ __launch_bounds__(256) void prep_b(
    const float* __restrict__ p,
    unsigned short* __restrict__ b_bf, float* __restrict__ p_sq,
    float* __restrict__ proto_out)
{
    const int row  = blockIdx.x * 4 + (threadIdx.x >> 6);
    const int lane = threadIdx.x & 63;

    const int g    = row >> 4;          // proto group 0..31
    const int l16p = row & 15;          // row within group

    const float4* src4 = (const float4*)(p + (size_t)row * K_DIM);
    float4* pout4 = (float4*)(proto_out + (size_t)row * K_DIM);

    float ssum = 0.0f;
#pragma unroll
    for (int j = 0; j < 3; ++j) {        // 192 float4 per row / 64 lanes
        const int idx = lane + j * 64;   // float4 index 0..191
        float4 v = src4[idx];
        ssum += v.x * v.x + v.y * v.y + v.z * v.z + v.w * v.w;
        ushort4 b;
        b.x = f2bf(v.x); b.y = f2bf(v.y); b.z = f2bf(v.z); b.w = f2bf(v.w);
        // fragment-major: element k -> block (g*24 + k>>5), slot
        // ((k>>3)&3)*16 + l16p (lane id), sub-offset k&7.
        const int k0   = idx * 4;               // first element of this ushort4
        const int kk   = k0 >> 5;               // k-step 0..23
        const int quad = (k0 >> 3) & 3;         // k-slice 0..3
        const int j0   = k0 & 7;                // 0 or 4
        const int dst  = (g * 24 + kk) * 512 + quad * 128 + l16p * 8 + j0;
        *(ushort4*)&b_bf[dst] = b;
        pout4[idx] = v;
    }
#pragma unroll
    for (int off = 32; off > 0; off >>= 1) ssum += __shfl_down(ssum, off);
    if (lane == 0) p_sq[row] = ssum;
}

__global__ __launch_bounds__(512, 2) void dist_main(
    const float* __restrict__ X,             // [M,K] fp32 tokens
    const unsigned short* __restrict__ Bb,   // fragment-major bf16 protos (ws)
    const float* __restrict__ p_sq,          // [N] fp32
    float* __restrict__ out)                 // [M,N] fp32 distances
{
    __shared__ unsigned short lds_a[32 * ASTR];   // 48.5 KB, 32-row full-K stripe
    __shared__ float lds_xsq[32];

    const int tid  = threadIdx.x;
    const int wave = tid >> 6;           // 0..7
    const int lane = tid & 63;
    const int bm   = blockIdx.x << 5;    // 32-row A stripe
    const int wn   = wave << 6;          // this wave's 64-col slice of N
    const int quad = lane >> 4;          // 0..3
    const int l16  = lane & 15;

    // ---- one-time A staging: fp32 -> (x_sq, bf16 LDS) ----
    const int ar = tid >> 4;             // 0..31 row
    const int ac = tid & 15;             // float4 col base
    const float* aptr = X + (size_t)(bm + ar) * K_DIM;
    float asq = 0.0f;
#pragma unroll
    for (int j = 0; j < 12; ++j) {
        const int c4 = ac + 16 * j;      // float4 index 0..191
        float4 v = *(const float4*)(aptr + (size_t)c4 * 4);
        asq += v.x * v.x + v.y * v.y + v.z * v.z + v.w * v.w;
        ushort4 u;
        u.x = f2bf(v.x); u.y = f2bf(v.y); u.z = f2bf(v.z); u.w = f2bf(v.w);
        *(ushort4*)&lds_a[ar * ASTR + c4 * 4] = u;
    }
#pragma unroll
    for (int off = 1; off < 16; off <<= 1) asq += __shfl_xor(asq, off);
    if (ac == 0) lds_xsq[ar] = asq;

    __syncthreads();   // the ONLY barrier

    // ---- barrier-free K-loop ----
    const f32x4 zero = {0.0f, 0.0f, 0.0f, 0.0f};
    f32x4 acc[2][4];
#pragma unroll
    for (int mt = 0; mt < 2; ++mt)
#pragma unroll
        for (int nt = 0; nt < 4; ++nt) acc[mt][nt] = zero;

    // fragment-major B: block (g*24 + kk) of 1KB; lane's 16B at lane*16.
    // wave's proto groups: g = wave*4 + nt.
    const unsigned short* bp = Bb + (size_t)lane * 8;
    const int gbase = (wave << 2) * 24;          // (wave*4)*24

    bf16x8 bcur[4], bnxt[4];
#pragma unroll
    for (int nt = 0; nt < 4; ++nt)
        bcur[nt] = *(const bf16x8*)(bp + (size_t)(gbase + nt * 24) * 512);

    for (int kc = 0; kc < NCH; ++kc) {
        const int k0 = kc * BK;
        if (kc + 1 < NCH) {
#pragma unroll
            for (int nt = 0; nt < 4; ++nt)
                bnxt[nt] = *(const bf16x8*)(bp
                    + (size_t)(gbase + nt * 24 + kc + 1) * 512);
        }

        bf16x8 af[2];
#pragma unroll
        for (int mt = 0; mt < 2; ++mt)
            af[mt] = *(const bf16x8*)&lds_a[(mt * 16 + l16) * ASTR + k0 + quad * 8];

#pragma unroll
        for (int mt = 0; mt < 2; ++mt)
#pragma unroll
            for (int nt = 0; nt < 4; ++nt)
                acc[mt][nt] = __builtin_amdgcn_mfma_f32_16x16x32_bf16(
                    af[mt], bcur[nt], acc[mt][nt], 0, 0, 0);

#pragma unroll
        for (int nt = 0; nt < 4; ++nt) bcur[nt] = bnxt[nt];
    }

    // ---- epilogue: C/D layout col = lane&15, row = quad*4 + i ----
    float ps[4];
#pragma unroll
    for (int nt = 0; nt < 4; ++nt) ps[nt] = p_sq[wn + nt * 16 + l16];

#pragma unroll
    for (int mt = 0; mt < 2; ++mt) {
#pragma unroll
        for (int i = 0; i < 4; ++i) {
            const int lr = mt * 16 + quad * 4 + i;   // local row 0..31
            const float xs = lds_xsq[lr];
            float* orow = out + (size_t)(bm + lr) * N_PROT + wn + l16;
#pragma unroll
            for (int nt = 0; nt < 4; ++nt)
                orow[nt * 16] = xs + ps[nt] - 2.0f * acc[mt][nt][i];
        }
    }
}

extern "C" void kernel_launch(void* const* d_in, const int* in_sizes, int n_in,
                              void* d_out, int out_size, void* d_ws, size_t ws_size,
                              hipStream_t stream) {
    const float* inputs = (const float*)d_in[0];   // [32,512,768] fp32
    const float* protos = (const float*)d_in[1];   // [512,768]    fp32
    float* out = (float*)d_out;
    float* proto_out = out + (size_t)M_TOK * N_PROT;   // second tuple element

    // ws layout: b_bf 512*768*2 = 786,432 B (fragment-major) ; p_sq 2,048 B
    char* ws = (char*)d_ws;
    unsigned short* b_bf = (unsigned short*)ws;
    float* p_sq = (float*)(ws + 786432);

    prep_b<<<128, 256, 0, stream>>>(protos, b_bf, p_sq, proto_out);
    // 512 blocks of 32-row stripes, 2 blocks/CU
    dist_main<<<M_TOK / 32, 512, 0, stream>>>(inputs, b_bf, p_sq, out);
}

// Round 7
// 102.587 us; speedup vs baseline: 1.0446x; 1.0446x over previous
//
#include <hip/hip_runtime.h>
#include <hip/hip_bf16.h>

// Problem: B=32, S=512, P=512, D=768
//   M = B*S = 16384 tokens, N = P = 512 prototypes, K = D = 768
// out[0 .. M*N)            = distances  ||x_m - p_n||^2  (fp32)
// out[M*N .. M*N + N*K)    = prototypes (fp32 passthrough)
//
// R12 = R10 (fragment-major B; best measured, dist_main ~31us) with
// 1024-thread blocks: 16 waves = 4/SIMD (was 8 waves = 2/SIMD).
//   R11 post-mortem: splitting M doubled B-traffic and halved per-wave
//   MFMA:B density -> regression. R12 keeps R10's structure bit-identical
//   (full-K 64-row stripe, ONE barrier, coalesced fragment-major B stream,
//   depth-1 B rotation, grid 256, B traffic 201MB, X read once) and only
//   re-divides the block: wave owns 64 tok x 32 protos (acc[4][2], 2
//   B-loads/k-step -> 8 MFMA : 2 loads, density preserved). 2x issue
//   parallelism in staging/epilogue, 4 waves/SIMD latency hiding in K-loop.

#define M_TOK 16384
#define N_PROT 512
#define K_DIM 768
#define BK 32
#define NCH (K_DIM / BK)     // 24
#define ASTR (K_DIM + 8)     // 776: padded LDS row stride in bf16 units

typedef __attribute__((ext_vector_type(4))) float f32x4;
typedef __attribute__((ext_vector_type(8))) short bf16x8;

__device__ inline unsigned short f2bf(float f) {
    // round-to-nearest-even on the bit pattern (finite inputs)
    unsigned int u = __float_as_uint(f);
    u += 0x7fffu + ((u >> 16) & 1u);
    return (unsigned short)(u >> 16);
}

// One wave per prototype row: bf16 convert (fragment-major store) + ||p||^2
// + fp32 passthrough copy.  (unchanged from verified R10)
__global__ __launch_bounds__(256) void prep_b(
    const float* __restrict__ p,
    unsigned short* __restrict__ b_bf, float* __restrict__ p_sq,
    float* __restrict__ proto_out)
{
    const int row  = blockIdx.x * 4 + (threadIdx.x >> 6);
    const int lane = threadIdx.x & 63;

    const int g    = row >> 4;          // proto group 0..31
    const int l16p = row & 15;          // row within group

    const float4* src4 = (const float4*)(p + (size_t)row * K_DIM);
    float4* pout4 = (float4*)(proto_out + (size_t)row * K_DIM);

    float ssum = 0.0f;
#pragma unroll
    for (int j = 0; j < 3; ++j) {        // 192 float4 per row / 64 lanes
        const int idx = lane + j * 64;   // float4 index 0..191
        float4 v = src4[idx];
        ssum += v.x * v.x + v.y * v.y + v.z * v.z + v.w * v.w;
        ushort4 b;
        b.x = f2bf(v.x); b.y = f2bf(v.y); b.z = f2bf(v.z); b.w = f2bf(v.w);
        // fragment-major: element k -> block (g*24 + k>>5), slot
        // ((k>>3)&3)*16 + l16p (lane id), sub-offset k&7.
        const int k0   = idx * 4;               // first element of this ushort4
        const int kk   = k0 >> 5;               // k-step 0..23
        const int quad = (k0 >> 3) & 3;         // k-slice 0..3
        const int j0   = k0 & 7;                // 0 or 4
        const int dst  = (g * 24 + kk) * 512 + quad * 128 + l16p * 8 + j0;
        *(ushort4*)&b_bf[dst] = b;
        pout4[idx] = v;
    }
#pragma unroll
    for (int off = 32; off > 0; off >>= 1) ssum += __shfl_down(ssum, off);
    if (lane == 0) p_sq[row] = ssum;
}

__global__ __launch_bounds__(1024, 4) void dist_main(
    const float* __restrict__ X,             // [M,K] fp32 tokens
    const unsigned short* __restrict__ Bb,   // fragment-major bf16 protos (ws)
    const float* __restrict__ p_sq,          // [N] fp32
    float* __restrict__ out)                 // [M,N] fp32 distances
{
    __shared__ unsigned short lds_a[64 * ASTR];   // ~97 KB, full-K A stripe
    __shared__ float lds_xsq[64];

    const int tid  = threadIdx.x;
    const int wave = tid >> 6;           // 0..15
    const int lane = tid & 63;
    const int bm   = blockIdx.x << 6;    // 64-row A stripe
    const int wn   = wave << 5;          // this wave's 32-col slice of N
    const int quad = lane >> 4;          // 0..3
    const int l16  = lane & 15;

    // ---- one-time A staging: fp32 -> (x_sq, bf16 LDS), 1024 threads ----
    const int ar = tid >> 4;             // 0..63 row
    const int ac = tid & 15;             // float4 col base
    const float* aptr = X + (size_t)(bm + ar) * K_DIM;
    float asq = 0.0f;
#pragma unroll
    for (int j = 0; j < 12; ++j) {
        const int c4 = ac + 16 * j;      // float4 index 0..191
        float4 v = *(const float4*)(aptr + (size_t)c4 * 4);
        asq += v.x * v.x + v.y * v.y + v.z * v.z + v.w * v.w;
        ushort4 u;
        u.x = f2bf(v.x); u.y = f2bf(v.y); u.z = f2bf(v.z); u.w = f2bf(v.w);
        *(ushort4*)&lds_a[ar * ASTR + c4 * 4] = u;
    }
#pragma unroll
    for (int off = 1; off < 16; off <<= 1) asq += __shfl_xor(asq, off);
    if (ac == 0) lds_xsq[ar] = asq;

    __syncthreads();   // the ONLY barrier

    // ---- barrier-free K-loop ----
    const f32x4 zero = {0.0f, 0.0f, 0.0f, 0.0f};
    f32x4 acc[4][2];
#pragma unroll
    for (int mt = 0; mt < 4; ++mt)
#pragma unroll
        for (int nt = 0; nt < 2; ++nt) acc[mt][nt] = zero;

    // fragment-major B: block (g*24 + kk) of 1KB; lane's 16B at lane*16.
    // wave's proto groups: g = wave*2 + nt (nt = 0,1).
    const unsigned short* bp = Bb + (size_t)lane * 8;
    const int gbase = (wave << 1) * 24;          // (wave*2)*24

    bf16x8 bcur[2], bnxt[2];
#pragma unroll
    for (int nt = 0; nt < 2; ++nt)
        bcur[nt] = *(const bf16x8*)(bp + (size_t)(gbase + nt * 24) * 512);

    for (int kc = 0; kc < NCH; ++kc) {
        const int k0 = kc * BK;
        if (kc + 1 < NCH) {
#pragma unroll
            for (int nt = 0; nt < 2; ++nt)
                bnxt[nt] = *(const bf16x8*)(bp
                    + (size_t)(gbase + nt * 24 + kc + 1) * 512);
        }

        bf16x8 af[4];
#pragma unroll
        for (int mt = 0; mt < 4; ++mt)
            af[mt] = *(const bf16x8*)&lds_a[(mt * 16 + l16) * ASTR + k0 + quad * 8];

#pragma unroll
        for (int mt = 0; mt < 4; ++mt)
#pragma unroll
            for (int nt = 0; nt < 2; ++nt)
                acc[mt][nt] = __builtin_amdgcn_mfma_f32_16x16x32_bf16(
                    af[mt], bcur[nt], acc[mt][nt], 0, 0, 0);

#pragma unroll
        for (int nt = 0; nt < 2; ++nt) bcur[nt] = bnxt[nt];
    }

    // ---- epilogue: C/D layout col = lane&15, row = quad*4 + i ----
    float ps[2];
#pragma unroll
    for (int nt = 0; nt < 2; ++nt) ps[nt] = p_sq[wn + nt * 16 + l16];

#pragma unroll
    for (int mt = 0; mt < 4; ++mt) {
#pragma unroll
        for (int i = 0; i < 4; ++i) {
            const int lr = mt * 16 + quad * 4 + i;   // local row 0..63
            const float xs = lds_xsq[lr];
            float* orow = out + (size_t)(bm + lr) * N_PROT + wn + l16;
#pragma unroll
            for (int nt = 0; nt < 2; ++nt)
                orow[nt * 16] = xs + ps[nt] - 2.0f * acc[mt][nt][i];
        }
    }
}

extern "C" void kernel_launch(void* const* d_in, const int* in_sizes, int n_in,
                              void* d_out, int out_size, void* d_ws, size_t ws_size,
                              hipStream_t stream) {
    const float* inputs = (const float*)d_in[0];   // [32,512,768] fp32
    const float* protos = (const float*)d_in[1];   // [512,768]    fp32
    float* out = (float*)d_out;
    float* proto_out = out + (size_t)M_TOK * N_PROT;   // second tuple element

    // ws layout: b_bf 512*768*2 = 786,432 B (fragment-major) ; p_sq 2,048 B
    char* ws = (char*)d_ws;
    unsigned short* b_bf = (unsigned short*)ws;
    float* p_sq = (float*)(ws + 786432);

    prep_b<<<128, 256, 0, stream>>>(protos, b_bf, p_sq, proto_out);
    dist_main<<<M_TOK / 64, 1024, 0, stream>>>(inputs, b_bf, p_sq, out);
}